// Round 5
// baseline (182.357 us; speedup 1.0000x reference)
//
#include <hip/hip_runtime.h>
#include <math.h>

#define BN_SCALE_F 0.99999500003749969f

// x: [N=64][T=300][C=64][V=25] fp32
// pooled: [N*C=4096][T=300]
// kern:   [4096][3]
// la:     [4096][300]
// W1P:    [75][600][4]  (W1P[k4][j][kk] = g_w1[j][k4*4+kk])
// lw1r:   [64][48]      (lw1r[c][o*3+k] = l_w1[o][c][k])

// ---------------- Kernel 0: weight repack (one-shot prep) ----------------
__global__ __launch_bounds__(256) void prep_kernel(const float* __restrict__ g_w1,
                                                   const float* __restrict__ l_w1,
                                                   float* __restrict__ w1p,
                                                   float* __restrict__ lw1r) {
  int b = blockIdx.x;
  if (b < 50) {
    __shared__ float tile[64][65];
    int tj = b % 10, tk = b / 10;
    int j0 = tj * 64, k0 = tk * 64;
    for (int it = 0; it < 16; ++it) {
      int i = threadIdx.x + it * 256;
      int jj = i >> 6, kk = i & 63;
      int j = j0 + jj, k = k0 + kk;
      tile[jj][kk] = (j < 600 && k < 300) ? g_w1[(size_t)j * 300 + k] : 0.f;
    }
    __syncthreads();
    for (int it = 0; it < 16; ++it) {
      int jloc = threadIdx.x >> 2;
      int kkm = threadIdx.x & 3;
      int kloc = it * 4 + kkm;
      int j = j0 + jloc, k = k0 + kloc;
      if (j < 600 && k < 300) {
        w1p[(size_t)(k >> 2) * 2400 + (size_t)j * 4 + (k & 3)] = tile[jloc][kloc];
      }
    }
    __syncthreads();
  } else {
    for (int i = threadIdx.x; i < 3072; i += 256) {
      int o = i / 192;
      int rem = i - o * 192;
      int c = rem / 3;
      int k = rem - c * 3;
      lw1r[c * 48 + o * 3 + k] = l_w1[i];
    }
  }
}

// ---------------- Kernel 1: mean over V ----------------
__global__ __launch_bounds__(256) void pool_kernel(const float* __restrict__ x,
                                                   float* __restrict__ pooled) {
  __shared__ float buf[6400];
  int bid = blockIdx.x;  // 0..4799, each covers 4 consecutive (n,t)
  const float4* src = (const float4*)(x + (size_t)bid * 6400);
  float4* b4 = (float4*)buf;
  for (int i = threadIdx.x; i < 1600; i += 256) b4[i] = src[i];
  __syncthreads();
  int wave = threadIdx.x >> 6;
  int c = threadIdx.x & 63;
  int nt = bid * 4 + wave;
  int n = nt / 300, t = nt - n * 300;
  const float* p = buf + wave * 1600 + c * 25;
  float s = 0.f;
#pragma unroll
  for (int v = 0; v < 25; ++v) s += p[v];
  pooled[((size_t)(n * 64 + c)) * 300 + t] = s * 0.04f;
}

// ---------------- Kernel 2: G branch (LDS rows + depth-3 weight prefetch) ----------------
#define GBLOCK(KK, WA, WB)                                 \
  {                                                        \
    _Pragma("unroll") for (int r = 0; r < 8; ++r) {        \
      float4 rv = *(const float4*)(&rows[r][(KK) * 4]);    \
      acc1[r] = fmaf(rv.x, WA.x, acc1[r]);                 \
      acc1[r] = fmaf(rv.y, WA.y, acc1[r]);                 \
      acc1[r] = fmaf(rv.z, WA.z, acc1[r]);                 \
      acc1[r] = fmaf(rv.w, WA.w, acc1[r]);                 \
      acc2[r] = fmaf(rv.x, WB.x, acc2[r]);                 \
      acc2[r] = fmaf(rv.y, WB.y, acc2[r]);                 \
      acc2[r] = fmaf(rv.z, WB.z, acc2[r]);                 \
      acc2[r] = fmaf(rv.w, WB.w, acc2[r]);                 \
    }                                                      \
  }

__global__ __launch_bounds__(320) void g_kernel(const float* __restrict__ pooled,
                                                const float* __restrict__ w1p,   // [75][600][4]
                                                const float* __restrict__ g_w2,  // [3][600]
                                                float* __restrict__ kern) {      // [4096][3]
  __shared__ float rows[8][300];
  __shared__ float wsum[5][24];
  int r0 = blockIdx.x * 8;
  int tid = threadIdx.x;
  {
    const float4* src = (const float4*)(pooled + (size_t)r0 * 300);
    float4* dst = (float4*)&rows[0][0];
    for (int i = tid; i < 600; i += 320) dst[i] = src[i];
  }
  __syncthreads();

  int j1 = tid;
  int j2 = tid + 320;
  bool has2 = (j2 < 600);
  int j2c = has2 ? j2 : j1;
  const float4* wp = (const float4*)w1p;  // [75][600]

  float acc1[8], acc2[8];
#pragma unroll
  for (int r = 0; r < 8; ++r) { acc1[r] = 0.f; acc2[r] = 0.f; }

  float4 w0a = wp[j1], w0b = wp[j2c];
  float4 w1a = wp[600 + j1], w1b = wp[600 + j2c];
  float4 w2a_ = wp[1200 + j1], w2b_ = wp[1200 + j2c];

  for (int k4 = 0; k4 < 75; k4 += 3) {
    int pa = k4 + 3; if (pa > 74) pa = 74;
    int pb = k4 + 4; if (pb > 74) pb = 74;
    int pc = k4 + 5; if (pc > 74) pc = 74;
    float4 na1 = wp[(size_t)pa * 600 + j1], nb1 = wp[(size_t)pa * 600 + j2c];
    float4 na2 = wp[(size_t)pb * 600 + j1], nb2 = wp[(size_t)pb * 600 + j2c];
    float4 na3 = wp[(size_t)pc * 600 + j1], nb3 = wp[(size_t)pc * 600 + j2c];
    GBLOCK(k4, w0a, w0b);
    GBLOCK(k4 + 1, w1a, w1b);
    GBLOCK(k4 + 2, w2a_, w2b_);
    w0a = na1; w0b = nb1;
    w1a = na2; w1b = nb2;
    w2a_ = na3; w2b_ = nb3;
  }

  float w2a0 = g_w2[j1], w2a1 = g_w2[600 + j1], w2a2 = g_w2[1200 + j1];
  float w2b0 = g_w2[j2c], w2b1 = g_w2[600 + j2c], w2b2 = g_w2[1200 + j2c];

  float lacc[24];
#pragma unroll
  for (int r = 0; r < 8; ++r) {
    float h1 = fmaxf(acc1[r] * BN_SCALE_F, 0.f);
    float h2 = has2 ? fmaxf(acc2[r] * BN_SCALE_F, 0.f) : 0.f;
    lacc[r * 3 + 0] = fmaf(h1, w2a0, h2 * w2b0);
    lacc[r * 3 + 1] = fmaf(h1, w2a1, h2 * w2b1);
    lacc[r * 3 + 2] = fmaf(h1, w2a2, h2 * w2b2);
  }

#pragma unroll
  for (int off = 1; off < 64; off <<= 1) {
#pragma unroll
    for (int i = 0; i < 24; ++i) lacc[i] += __shfl_xor(lacc[i], off, 64);
  }
  int wave = tid >> 6;
  int lane = tid & 63;
  if (lane == 0) {
#pragma unroll
    for (int i = 0; i < 24; ++i) wsum[wave][i] = lacc[i];
  }
  __syncthreads();
  if (wave == 0) {
    float s = 0.f;
    if (lane < 24) {
#pragma unroll
      for (int w = 0; w < 5; ++w) s += wsum[w][lane];
    }
    float a = __shfl(s, lane * 3 + 0, 64);
    float b = __shfl(s, lane * 3 + 1, 64);
    float c = __shfl(s, lane * 3 + 2, 64);
    if (lane < 8) {
      float m = fmaxf(a, fmaxf(b, c));
      float ea = expf(a - m), eb = expf(b - m), ec = expf(c - m);
      float inv = 1.f / (ea + eb + ec);
      size_t o = (size_t)(r0 + lane) * 3;
      kern[o] = ea * inv;
      kern[o + 1] = eb * inv;
      kern[o + 2] = ec * inv;
    }
  }
}

// ---------------- Kernel 3: L branch ----------------
__global__ __launch_bounds__(320) void l_kernel(const float* __restrict__ pooled,
                                                const float* __restrict__ lw1r,  // [64][48]
                                                const float* __restrict__ l_w2,  // [64][16]
                                                float* __restrict__ la) {        // [4096][300]
  __shared__ float p[64][304];
  __shared__ float z[16][300];
  int n = blockIdx.x;
  for (int i = threadIdx.x; i < 64 * 304; i += 320) {
    int c = i / 304, tp = i - c * 304;
    p[c][tp] = (tp >= 1 && tp <= 300) ? pooled[(size_t)(n * 64 + c) * 300 + (tp - 1)] : 0.f;
  }
  __syncthreads();
  int t = threadIdx.x;
  if (t < 300) {
    float acc[16];
#pragma unroll
    for (int o = 0; o < 16; ++o) acc[o] = 0.f;
    for (int c = 0; c < 64; ++c) {
      const float* wr = lw1r + c * 48;
      float pk0 = p[c][t];
      float pk1 = p[c][t + 1];
      float pk2 = p[c][t + 2];
#pragma unroll
      for (int o = 0; o < 16; ++o) {
        acc[o] = fmaf(wr[o * 3 + 0], pk0, acc[o]);
        acc[o] = fmaf(wr[o * 3 + 1], pk1, acc[o]);
        acc[o] = fmaf(wr[o * 3 + 2], pk2, acc[o]);
      }
    }
#pragma unroll
    for (int o = 0; o < 16; ++o) {
      float v = acc[o] * BN_SCALE_F;
      z[o][t] = v > 0.f ? v : 0.f;
    }
  }
  __syncthreads();
  {
    int c = threadIdx.x / 5;
    int t4b = threadIdx.x - c * 5;
    const float* w2row = l_w2 + c * 16;
    float w2r[16];
#pragma unroll
    for (int o = 0; o < 16; ++o) w2r[o] = w2row[o];
    float* outp = la + ((size_t)(n * 64 + c)) * 300;
    for (int it = 0; it < 15; ++it) {
      int t4 = t4b + it * 5;
      float4 s = {0.f, 0.f, 0.f, 0.f};
#pragma unroll
      for (int o = 0; o < 16; ++o) {
        float4 zv = *(const float4*)(&z[o][t4 * 4]);
        float wo = w2r[o];
        s.x = fmaf(zv.x, wo, s.x);
        s.y = fmaf(zv.y, wo, s.y);
        s.z = fmaf(zv.z, wo, s.z);
        s.w = fmaf(zv.w, wo, s.w);
      }
      float4 r;
      r.x = 1.f / (1.f + expf(-s.x));
      r.y = 1.f / (1.f + expf(-s.y));
      r.z = 1.f / (1.f + expf(-s.z));
      r.w = 1.f / (1.f + expf(-s.w));
      *(float4*)(&outp[t4 * 4]) = r;
    }
  }
}

// ---------------- Kernel 4: final conv, 4-step software pipeline ----------------
// Thread owns one float4 column (cv4 in 0..399) over a 20-long t chunk.
// Per group of 4 t-steps: 4 x-float4 + 8 la scalars issued together, then VALU burst.
__global__ __launch_bounds__(256) void tam_final_kernel(const float* __restrict__ x,
                                                        const float* __restrict__ la,
                                                        const float* __restrict__ kern,
                                                        float* __restrict__ out) {
  int bid = blockIdx.x;  // 64 n * 15 tchunk * 2 half = 1920
  int n = bid / 30;
  int rem = bid - n * 30;
  int tch = rem >> 1;  // 0..14
  int half = rem & 1;
  int cv4 = half * 256 + threadIdx.x;
  if (cv4 >= 400) return;
  int e0 = cv4 * 4;
  int c0 = e0 / 25;
  int c3 = (e0 + 3) / 25;
  bool s1 = ((e0 + 1) / 25) != c0;
  bool s2 = ((e0 + 2) / 25) != c0;
  bool s3 = (c3 != c0);
  const float* lap0 = la + (size_t)(n * 64 + c0) * 300;
  const float* lap1 = la + (size_t)(n * 64 + c3) * 300;
  const float* kp0 = kern + (size_t)(n * 64 + c0) * 3;
  const float* kp1 = kern + (size_t)(n * 64 + c3) * 3;
  float k00 = kp0[0], k01 = kp0[1], k02 = kp0[2];
  float k10 = kp1[0], k11 = kp1[1], k12 = kp1[2];
  float4 K0 = {k00, s1 ? k10 : k00, s2 ? k10 : k00, s3 ? k10 : k00};
  float4 K1 = {k01, s1 ? k11 : k01, s2 ? k11 : k01, s3 ? k11 : k01};
  float4 K2 = {k02, s1 ? k12 : k02, s2 ? k12 : k02, s3 ? k12 : k02};

  const float4* xp = (const float4*)(x + (size_t)n * 480000) + cv4;
  float4* op = (float4*)(out + (size_t)n * 480000) + cv4;

  int t0 = tch * 20;

#define YMAKE(dst, XV, L0, L1)          \
  dst.x = XV.x * (L0);                  \
  dst.y = XV.y * (s1 ? (L1) : (L0));    \
  dst.z = XV.z * (s2 ? (L1) : (L0));    \
  dst.w = XV.w * (s3 ? (L1) : (L0));

  float4 ym, yc;
  if (t0 > 0) {
    float l0 = lap0[t0 - 1], l1 = lap1[t0 - 1];
    float4 xv = xp[(size_t)(t0 - 1) * 400];
    YMAKE(ym, xv, l0, l1);
  } else {
    ym = {0.f, 0.f, 0.f, 0.f};
  }
  {
    float l0 = lap0[t0], l1 = lap1[t0];
    float4 xv = xp[(size_t)t0 * 400];
    YMAKE(yc, xv, l0, l1);
  }

  for (int g = 0; g < 5; ++g) {
    int t = t0 + g * 4;
    int ta = t + 1, tb = t + 2, tc = t + 3, td = t + 4;
    int tdc = td < 300 ? td : 299;
    // issue all loads for the group
    float4 xa = xp[(size_t)ta * 400];
    float4 xb = xp[(size_t)tb * 400];
    float4 xc = xp[(size_t)tc * 400];
    float4 xd = xp[(size_t)tdc * 400];
    float a0 = lap0[ta], a1 = lap1[ta];
    float b0 = lap0[tb], b1 = lap1[tb];
    float c0_ = lap0[tc], c1_ = lap1[tc];
    float d0 = lap0[tdc], d1 = lap1[tdc];

    float4 y1, y2, y3, y4;
    YMAKE(y1, xa, a0, a1);
    YMAKE(y2, xb, b0, b1);
    YMAKE(y3, xc, c0_, c1_);
    if (td < 300) {
      YMAKE(y4, xd, d0, d1);
    } else {
      y4 = {0.f, 0.f, 0.f, 0.f};
    }

    float4 o0, o1, o2, o3;
    o0.x = fmaf(ym.x, K0.x, fmaf(yc.x, K1.x, y1.x * K2.x));
    o0.y = fmaf(ym.y, K0.y, fmaf(yc.y, K1.y, y1.y * K2.y));
    o0.z = fmaf(ym.z, K0.z, fmaf(yc.z, K1.z, y1.z * K2.z));
    o0.w = fmaf(ym.w, K0.w, fmaf(yc.w, K1.w, y1.w * K2.w));
    o1.x = fmaf(yc.x, K0.x, fmaf(y1.x, K1.x, y2.x * K2.x));
    o1.y = fmaf(yc.y, K0.y, fmaf(y1.y, K1.y, y2.y * K2.y));
    o1.z = fmaf(yc.z, K0.z, fmaf(y1.z, K1.z, y2.z * K2.z));
    o1.w = fmaf(yc.w, K0.w, fmaf(y1.w, K1.w, y2.w * K2.w));
    o2.x = fmaf(y1.x, K0.x, fmaf(y2.x, K1.x, y3.x * K2.x));
    o2.y = fmaf(y1.y, K0.y, fmaf(y2.y, K1.y, y3.y * K2.y));
    o2.z = fmaf(y1.z, K0.z, fmaf(y2.z, K1.z, y3.z * K2.z));
    o2.w = fmaf(y1.w, K0.w, fmaf(y2.w, K1.w, y3.w * K2.w));
    o3.x = fmaf(y2.x, K0.x, fmaf(y3.x, K1.x, y4.x * K2.x));
    o3.y = fmaf(y2.y, K0.y, fmaf(y3.y, K1.y, y4.y * K2.y));
    o3.z = fmaf(y2.z, K0.z, fmaf(y3.z, K1.z, y4.z * K2.z));
    o3.w = fmaf(y2.w, K0.w, fmaf(y3.w, K1.w, y4.w * K2.w));

    op[(size_t)t * 400] = o0;
    op[(size_t)(t + 1) * 400] = o1;
    op[(size_t)(t + 2) * 400] = o2;
    op[(size_t)(t + 3) * 400] = o3;

    ym = y3;
    yc = y4;
  }
#undef YMAKE
}

extern "C" void kernel_launch(void* const* d_in, const int* in_sizes, int n_in,
                              void* d_out, int out_size, void* d_ws, size_t ws_size,
                              hipStream_t stream) {
  const float* x = (const float*)d_in[0];
  const float* g_w1 = (const float*)d_in[1];
  const float* g_w2 = (const float*)d_in[2];
  const float* l_w1 = (const float*)d_in[3];
  const float* l_w2 = (const float*)d_in[4];
  float* out = (float*)d_out;
  float* ws = (float*)d_ws;
  float* pooled = ws;                           // 1,228,800 floats
  float* kern = ws + 1228800;                   // 12,288
  float* lact = ws + 1228800 + 12288;           // 1,228,800
  float* w1p = ws + 1228800 + 12288 + 1228800;  // 180,000
  float* lw1r = w1p + 180000;                   // 3,072

  hipLaunchKernelGGL(prep_kernel, dim3(51), dim3(256), 0, stream, g_w1, l_w1, w1p, lw1r);
  hipLaunchKernelGGL(pool_kernel, dim3(4800), dim3(256), 0, stream, x, pooled);
  hipLaunchKernelGGL(g_kernel, dim3(512), dim3(320), 0, stream, pooled, w1p, g_w2, kern);
  hipLaunchKernelGGL(l_kernel, dim3(64), dim3(320), 0, stream, pooled, lw1r, l_w2, lact);
  hipLaunchKernelGGL(tam_final_kernel, dim3(1920), dim3(256), 0, stream, x, lact, kern, out);
}

// Round 6
// 171.736 us; speedup vs baseline: 1.0618x; 1.0618x over previous
//
#include <hip/hip_runtime.h>
#include <math.h>

#define BN_SCALE_F 0.99999500003749969f

// x: [N=64][T=300][C=64][V=25] fp32
// pooled: [N*C=4096][T=300]
// kern:   [4096][3]
// la:     [4096][300]
// W1P:    [75][600][4]  (W1P[k4][j][kk] = g_w1[j][k4*4+kk])
// lw1r:   [64][48]      (lw1r[c][o*3+k] = l_w1[o][c][k])

// ---------------- Kernel 1: mean over V (blocks 0..4799) + weight repack (4800..4850) ----------------
__global__ __launch_bounds__(256) void pool_prep_kernel(const float* __restrict__ x,
                                                        const float* __restrict__ g_w1,
                                                        const float* __restrict__ l_w1,
                                                        float* __restrict__ pooled,
                                                        float* __restrict__ w1p,
                                                        float* __restrict__ lw1r) {
  __shared__ float buf[6400];
  int bid = blockIdx.x;
  if (bid < 4800) {
    const float4* src = (const float4*)(x + (size_t)bid * 6400);
    float4* b4 = (float4*)buf;
    for (int i = threadIdx.x; i < 1600; i += 256) b4[i] = src[i];
    __syncthreads();
    int wave = threadIdx.x >> 6;
    int c = threadIdx.x & 63;
    int nt = bid * 4 + wave;
    int n = nt / 300, t = nt - n * 300;
    const float* p = buf + wave * 1600 + c * 25;
    float s = 0.f;
#pragma unroll
    for (int v = 0; v < 25; ++v) s += p[v];
    pooled[((size_t)(n * 64 + c)) * 300 + t] = s * 0.04f;
  } else if (bid < 4850) {
    int b = bid - 4800;  // 0..49: transpose g_w1 tile 64x64
    float* tile = buf;   // [64][65]
    int tj = b % 10, tk = b / 10;
    int j0 = tj * 64, k0 = tk * 64;
    for (int it = 0; it < 16; ++it) {
      int i = threadIdx.x + it * 256;
      int jj = i >> 6, kk = i & 63;
      int j = j0 + jj, k = k0 + kk;
      tile[jj * 65 + kk] = (j < 600 && k < 300) ? g_w1[(size_t)j * 300 + k] : 0.f;
    }
    __syncthreads();
    for (int it = 0; it < 16; ++it) {
      int jloc = threadIdx.x >> 2;
      int kkm = threadIdx.x & 3;
      int kloc = it * 4 + kkm;
      int j = j0 + jloc, k = k0 + kloc;
      if (j < 600 && k < 300) {
        w1p[(size_t)(k >> 2) * 2400 + (size_t)j * 4 + (k & 3)] = tile[jloc * 65 + kloc];
      }
    }
  } else {
    // repack l_w1 [16][64][3] -> [64][48]
    for (int i = threadIdx.x; i < 3072; i += 256) {
      int o = i / 192;
      int rem = i - o * 192;
      int c = rem / 3;
      int k = rem - c * 3;
      lw1r[c * 48 + o * 3 + k] = l_w1[i];
    }
  }
}

// ---------------- Kernel 2: G branch (16 rows/block -> halved L2 weight traffic) ----------------
__global__ __launch_bounds__(320) void g_kernel(const float* __restrict__ pooled,
                                                const float* __restrict__ w1p,   // [75][600][4]
                                                const float* __restrict__ g_w2,  // [3][600]
                                                float* __restrict__ kern) {      // [4096][3]
  __shared__ float rows[16][300];
  __shared__ float wsum[5][48];
  int r0 = blockIdx.x * 16;
  int tid = threadIdx.x;
  {
    const float4* src = (const float4*)(pooled + (size_t)r0 * 300);
    float4* dst = (float4*)&rows[0][0];
    for (int i = tid; i < 1200; i += 320) dst[i] = src[i];
  }
  __syncthreads();

  int j1 = tid;
  int j2 = tid + 320;
  bool has2 = (j2 < 600);
  int j2c = has2 ? j2 : j1;
  const float4* wp = (const float4*)w1p;  // [75][600]

  float acc1[16], acc2[16];
#pragma unroll
  for (int r = 0; r < 16; ++r) { acc1[r] = 0.f; acc2[r] = 0.f; }

  float4 wa = wp[j1];
  float4 wb = wp[j2c];
  for (int k4 = 0; k4 < 75; ++k4) {
    int nk = (k4 < 74) ? k4 + 1 : 74;
    float4 wan = wp[(size_t)nk * 600 + j1];
    float4 wbn = wp[(size_t)nk * 600 + j2c];
#pragma unroll
    for (int r = 0; r < 16; ++r) {
      float4 rv = *(const float4*)(&rows[r][k4 * 4]);  // uniform -> LDS broadcast
      acc1[r] = fmaf(rv.x, wa.x, acc1[r]);
      acc1[r] = fmaf(rv.y, wa.y, acc1[r]);
      acc1[r] = fmaf(rv.z, wa.z, acc1[r]);
      acc1[r] = fmaf(rv.w, wa.w, acc1[r]);
      acc2[r] = fmaf(rv.x, wb.x, acc2[r]);
      acc2[r] = fmaf(rv.y, wb.y, acc2[r]);
      acc2[r] = fmaf(rv.z, wb.z, acc2[r]);
      acc2[r] = fmaf(rv.w, wb.w, acc2[r]);
    }
    wa = wan;
    wb = wbn;
  }

  float w2a0 = g_w2[j1], w2a1 = g_w2[600 + j1], w2a2 = g_w2[1200 + j1];
  float w2b0 = g_w2[j2c], w2b1 = g_w2[600 + j2c], w2b2 = g_w2[1200 + j2c];

  float lacc[48];
#pragma unroll
  for (int r = 0; r < 16; ++r) {
    float h1 = fmaxf(acc1[r] * BN_SCALE_F, 0.f);
    float h2 = has2 ? fmaxf(acc2[r] * BN_SCALE_F, 0.f) : 0.f;
    lacc[r * 3 + 0] = fmaf(h1, w2a0, h2 * w2b0);
    lacc[r * 3 + 1] = fmaf(h1, w2a1, h2 * w2b1);
    lacc[r * 3 + 2] = fmaf(h1, w2a2, h2 * w2b2);
  }

#pragma unroll
  for (int off = 1; off < 64; off <<= 1) {
#pragma unroll
    for (int i = 0; i < 48; ++i) lacc[i] += __shfl_xor(lacc[i], off, 64);
  }
  int wave = tid >> 6;
  int lane = tid & 63;
  if (lane == 0) {
#pragma unroll
    for (int i = 0; i < 48; ++i) wsum[wave][i] = lacc[i];
  }
  __syncthreads();
  if (wave == 0) {
    float s = 0.f;
    if (lane < 48) {
#pragma unroll
      for (int w = 0; w < 5; ++w) s += wsum[w][lane];
    }
    float a = __shfl(s, lane * 3 + 0, 64);
    float b = __shfl(s, lane * 3 + 1, 64);
    float c = __shfl(s, lane * 3 + 2, 64);
    if (lane < 16) {
      float m = fmaxf(a, fmaxf(b, c));
      float ea = expf(a - m), eb = expf(b - m), ec = expf(c - m);
      float inv = 1.f / (ea + eb + ec);
      size_t o = (size_t)(r0 + lane) * 3;
      kern[o] = ea * inv;
      kern[o + 1] = eb * inv;
      kern[o + 2] = ec * inv;
    }
  }
}

// ---------------- Kernel 3: L branch ----------------
__global__ __launch_bounds__(320) void l_kernel(const float* __restrict__ pooled,
                                                const float* __restrict__ lw1r,  // [64][48]
                                                const float* __restrict__ l_w2,  // [64][16]
                                                float* __restrict__ la) {        // [4096][300]
  __shared__ float p[64][304];
  __shared__ float z[16][300];
  int n = blockIdx.x;
  for (int i = threadIdx.x; i < 64 * 304; i += 320) {
    int c = i / 304, tp = i - c * 304;
    p[c][tp] = (tp >= 1 && tp <= 300) ? pooled[(size_t)(n * 64 + c) * 300 + (tp - 1)] : 0.f;
  }
  __syncthreads();
  int t = threadIdx.x;
  if (t < 300) {
    float acc[16];
#pragma unroll
    for (int o = 0; o < 16; ++o) acc[o] = 0.f;
    for (int c = 0; c < 64; ++c) {
      const float* wr = lw1r + c * 48;  // uniform -> s_load into SGPRs
      float pk0 = p[c][t];
      float pk1 = p[c][t + 1];
      float pk2 = p[c][t + 2];
#pragma unroll
      for (int o = 0; o < 16; ++o) {
        acc[o] = fmaf(wr[o * 3 + 0], pk0, acc[o]);
        acc[o] = fmaf(wr[o * 3 + 1], pk1, acc[o]);
        acc[o] = fmaf(wr[o * 3 + 2], pk2, acc[o]);
      }
    }
#pragma unroll
    for (int o = 0; o < 16; ++o) {
      float v = acc[o] * BN_SCALE_F;
      z[o][t] = v > 0.f ? v : 0.f;
    }
  }
  __syncthreads();
  {
    int c = threadIdx.x / 5;
    int t4b = threadIdx.x - c * 5;
    const float* w2row = l_w2 + c * 16;
    float w2r[16];
#pragma unroll
    for (int o = 0; o < 16; ++o) w2r[o] = w2row[o];
    float* outp = la + ((size_t)(n * 64 + c)) * 300;
    for (int it = 0; it < 15; ++it) {
      int t4 = t4b + it * 5;
      float4 s = {0.f, 0.f, 0.f, 0.f};
#pragma unroll
      for (int o = 0; o < 16; ++o) {
        float4 zv = *(const float4*)(&z[o][t4 * 4]);
        float wo = w2r[o];
        s.x = fmaf(zv.x, wo, s.x);
        s.y = fmaf(zv.y, wo, s.y);
        s.z = fmaf(zv.z, wo, s.z);
        s.w = fmaf(zv.w, wo, s.w);
      }
      float4 r;
      r.x = 1.f / (1.f + expf(-s.x));
      r.y = 1.f / (1.f + expf(-s.y));
      r.z = 1.f / (1.f + expf(-s.z));
      r.w = 1.f / (1.f + expf(-s.w));
      *(float4*)(&outp[t4 * 4]) = r;
    }
  }
}

// ---------------- Kernel 4: final depthwise temporal conv (round-4 float4 form) ----------------
__global__ __launch_bounds__(256) void tam_final_kernel(const float* __restrict__ x,
                                                        const float* __restrict__ la,
                                                        const float* __restrict__ kern,
                                                        float* __restrict__ out) {
  int bid = blockIdx.x;  // 64 n * 8 tchunk * 2 half
  int n = bid >> 4;
  int rem = bid & 15;
  int tch = rem >> 1;
  int half = rem & 1;
  int cv4 = half * 256 + threadIdx.x;
  if (cv4 >= 400) return;
  int e0 = cv4 * 4;
  int c0 = e0 / 25;
  int c3 = (e0 + 3) / 25;
  bool s1 = ((e0 + 1) / 25) != c0;
  bool s2 = ((e0 + 2) / 25) != c0;
  bool s3 = (c3 != c0);
  const float* lap0 = la + (size_t)(n * 64 + c0) * 300;
  const float* lap1 = la + (size_t)(n * 64 + c3) * 300;
  const float* kp0 = kern + (size_t)(n * 64 + c0) * 3;
  const float* kp1 = kern + (size_t)(n * 64 + c3) * 3;
  float k00 = kp0[0], k01 = kp0[1], k02 = kp0[2];
  float k10 = kp1[0], k11 = kp1[1], k12 = kp1[2];
  float4 K0 = {k00, s1 ? k10 : k00, s2 ? k10 : k00, s3 ? k10 : k00};
  float4 K1 = {k01, s1 ? k11 : k01, s2 ? k11 : k01, s3 ? k11 : k01};
  float4 K2 = {k02, s1 ? k12 : k02, s2 ? k12 : k02, s3 ? k12 : k02};

  const float4* xp = (const float4*)(x + (size_t)n * 480000) + cv4;  // +t*400
  float4* op = (float4*)(out + (size_t)n * 480000) + cv4;

  int t0 = tch * 38;
  int tend = t0 + 38;
  if (tend > 300) tend = 300;

#define LAMUL(dst, t)                                        \
  {                                                          \
    float l0 = lap0[(t)];                                    \
    float l1 = lap1[(t)];                                    \
    float4 xv = xp[(size_t)(t) * 400];                       \
    dst.x = xv.x * l0;                                       \
    dst.y = xv.y * (s1 ? l1 : l0);                           \
    dst.z = xv.z * (s2 ? l1 : l0);                           \
    dst.w = xv.w * (s3 ? l1 : l0);                           \
  }

  float4 am, ac, an;
  if (t0 > 0) {
    LAMUL(am, t0 - 1);
  } else {
    am = {0.f, 0.f, 0.f, 0.f};
  }
  LAMUL(ac, t0);
  for (int t = t0; t < tend; ++t) {
    if (t + 1 < 300) {
      LAMUL(an, t + 1);
    } else {
      an = {0.f, 0.f, 0.f, 0.f};
    }
    float4 o;
    o.x = fmaf(am.x, K0.x, fmaf(ac.x, K1.x, an.x * K2.x));
    o.y = fmaf(am.y, K0.y, fmaf(ac.y, K1.y, an.y * K2.y));
    o.z = fmaf(am.z, K0.z, fmaf(ac.z, K1.z, an.z * K2.z));
    o.w = fmaf(am.w, K0.w, fmaf(ac.w, K1.w, an.w * K2.w));
    op[(size_t)t * 400] = o;
    am = ac;
    ac = an;
  }
#undef LAMUL
}

extern "C" void kernel_launch(void* const* d_in, const int* in_sizes, int n_in,
                              void* d_out, int out_size, void* d_ws, size_t ws_size,
                              hipStream_t stream) {
  const float* x = (const float*)d_in[0];
  const float* g_w1 = (const float*)d_in[1];
  const float* g_w2 = (const float*)d_in[2];
  const float* l_w1 = (const float*)d_in[3];
  const float* l_w2 = (const float*)d_in[4];
  float* out = (float*)d_out;
  float* ws = (float*)d_ws;
  float* pooled = ws;                           // 1,228,800 floats
  float* kern = ws + 1228800;                   // 12,288
  float* lact = ws + 1228800 + 12288;           // 1,228,800
  float* w1p = ws + 1228800 + 12288 + 1228800;  // 180,000
  float* lw1r = w1p + 180000;                   // 3,072

  hipLaunchKernelGGL(pool_prep_kernel, dim3(4851), dim3(256), 0, stream, x, g_w1, l_w1,
                     pooled, w1p, lw1r);
  hipLaunchKernelGGL(g_kernel, dim3(256), dim3(320), 0, stream, pooled, w1p, g_w2, kern);
  hipLaunchKernelGGL(l_kernel, dim3(64), dim3(320), 0, stream, pooled, lw1r, l_w2, lact);
  hipLaunchKernelGGL(tam_final_kernel, dim3(1024), dim3(256), 0, stream, x, lact, kern, out);
}

// Round 7
// 170.541 us; speedup vs baseline: 1.0693x; 1.0070x over previous
//
#include <hip/hip_runtime.h>
#include <math.h>

#define BN_SCALE_F 0.99999500003749969f

// x: [N=64][T=300][C=64][V=25] fp32
// pooled: [N*C=4096][T=300]
// kern:   [4096][3]
// la:     [4096][300]
// W1P:    [75][600][4]  (W1P[k4][j][kk] = g_w1[j][k4*4+kk])
// lw1r:   [64][48]      (lw1r[c][o*3+k] = l_w1[o][c][k])

// ---------------- Kernel 1: mean over V (blocks 0..4799) + weight repack (4800..4850) ----------------
__global__ __launch_bounds__(256) void pool_prep_kernel(const float* __restrict__ x,
                                                        const float* __restrict__ g_w1,
                                                        const float* __restrict__ l_w1,
                                                        float* __restrict__ pooled,
                                                        float* __restrict__ w1p,
                                                        float* __restrict__ lw1r) {
  __shared__ float buf[6400];
  int bid = blockIdx.x;
  if (bid < 4800) {
    const float4* src = (const float4*)(x + (size_t)bid * 6400);
    float4* b4 = (float4*)buf;
    for (int i = threadIdx.x; i < 1600; i += 256) b4[i] = src[i];
    __syncthreads();
    int wave = threadIdx.x >> 6;
    int c = threadIdx.x & 63;
    int nt = bid * 4 + wave;
    int n = nt / 300, t = nt - n * 300;
    const float* p = buf + wave * 1600 + c * 25;
    float s = 0.f;
#pragma unroll
    for (int v = 0; v < 25; ++v) s += p[v];
    pooled[((size_t)(n * 64 + c)) * 300 + t] = s * 0.04f;
  } else if (bid < 4850) {
    int b = bid - 4800;  // 0..49: transpose g_w1 tile 64x64
    float* tile = buf;   // [64][65]
    int tj = b % 10, tk = b / 10;
    int j0 = tj * 64, k0 = tk * 64;
    for (int it = 0; it < 16; ++it) {
      int i = threadIdx.x + it * 256;
      int jj = i >> 6, kk = i & 63;
      int j = j0 + jj, k = k0 + kk;
      tile[jj * 65 + kk] = (j < 600 && k < 300) ? g_w1[(size_t)j * 300 + k] : 0.f;
    }
    __syncthreads();
    for (int it = 0; it < 16; ++it) {
      int jloc = threadIdx.x >> 2;
      int kkm = threadIdx.x & 3;
      int kloc = it * 4 + kkm;
      int j = j0 + jloc, k = k0 + kloc;
      if (j < 600 && k < 300) {
        w1p[(size_t)(k >> 2) * 2400 + (size_t)j * 4 + (k & 3)] = tile[jloc * 65 + kloc];
      }
    }
  } else {
    // repack l_w1 [16][64][3] -> [64][48]
    for (int i = threadIdx.x; i < 3072; i += 256) {
      int o = i / 192;
      int rem = i - o * 192;
      int c = rem / 3;
      int k = rem - c * 3;
      lw1r[c * 48 + o * 3 + k] = l_w1[i];
    }
  }
}

// ---------------- Kernel 2: G branch ----------------
// 16 rows/block, 256 blocks, 640 threads (10 waves/CU). 1 col/thread, depth-2 weight
// prefetch, acc[16] in regs. Tail: h -> LDS, per-wave dot for the 48 (row,k) logits.
__global__ __launch_bounds__(640) void g_kernel(const float* __restrict__ pooled,
                                                const float* __restrict__ w1p,   // [75][600][4]
                                                const float* __restrict__ g_w2,  // [3][600]
                                                float* __restrict__ kern) {      // [4096][3]
  __shared__ float rows[16][300];   // 19.2 KB
  __shared__ float hbuf[16][640];   // 40.96 KB (cols >=600 zeroed)
  __shared__ float logits[48];
  int r0 = blockIdx.x * 16;
  int tid = threadIdx.x;
  {
    const float4* src = (const float4*)(pooled + (size_t)r0 * 300);
    float4* dst = (float4*)&rows[0][0];
    for (int i = tid; i < 1200; i += 640) dst[i] = src[i];
  }
  __syncthreads();

  int j = tid;
  int jc = (j < 600) ? j : 599;
  const float4* wp = (const float4*)w1p;  // [75][600]

  float acc[16];
#pragma unroll
  for (int r = 0; r < 16; ++r) acc[r] = 0.f;

  float4 w0 = wp[jc];
  float4 w1 = wp[600 + jc];
  for (int k4 = 0; k4 < 75; ++k4) {
    int nk = k4 + 2;
    if (nk > 74) nk = 74;
    float4 wn = wp[(size_t)nk * 600 + jc];
#pragma unroll
    for (int r = 0; r < 16; ++r) {
      float4 rv = *(const float4*)(&rows[r][k4 * 4]);  // wave-uniform LDS broadcast
      acc[r] = fmaf(rv.x, w0.x, acc[r]);
      acc[r] = fmaf(rv.y, w0.y, acc[r]);
      acc[r] = fmaf(rv.z, w0.z, acc[r]);
      acc[r] = fmaf(rv.w, w0.w, acc[r]);
    }
    w0 = w1;
    w1 = wn;
  }

#pragma unroll
  for (int r = 0; r < 16; ++r) {
    float h = fmaxf(acc[r] * BN_SCALE_F, 0.f);
    hbuf[r][j] = (j < 600) ? h : 0.f;
  }
  __syncthreads();

  int wave = tid >> 6, lane = tid & 63;
  for (int o = wave; o < 48; o += 10) {
    int r = o / 3, k = o - r * 3;
    float s = 0.f;
#pragma unroll
    for (int q = 0; q < 10; ++q) {
      int jj = lane + q * 64;
      float wz = (jj < 600) ? g_w2[k * 600 + jj] : 0.f;
      s = fmaf(hbuf[r][jj], wz, s);
    }
#pragma unroll
    for (int off = 1; off < 64; off <<= 1) s += __shfl_xor(s, off, 64);
    if (lane == 0) logits[o] = s;
  }
  __syncthreads();
  if (tid < 16) {
    float a = logits[tid * 3 + 0], b = logits[tid * 3 + 1], c = logits[tid * 3 + 2];
    float m = fmaxf(a, fmaxf(b, c));
    float ea = expf(a - m), eb = expf(b - m), ec = expf(c - m);
    float inv = 1.f / (ea + eb + ec);
    size_t oo = (size_t)(r0 + tid) * 3;
    kern[oo] = ea * inv;
    kern[oo + 1] = eb * inv;
    kern[oo + 2] = ec * inv;
  }
}

// ---------------- Kernel 3: L branch ----------------
__global__ __launch_bounds__(320) void l_kernel(const float* __restrict__ pooled,
                                                const float* __restrict__ lw1r,  // [64][48]
                                                const float* __restrict__ l_w2,  // [64][16]
                                                float* __restrict__ la) {        // [4096][300]
  __shared__ float p[64][304];
  __shared__ float z[16][300];
  int n = blockIdx.x;
  for (int i = threadIdx.x; i < 64 * 304; i += 320) {
    int c = i / 304, tp = i - c * 304;
    p[c][tp] = (tp >= 1 && tp <= 300) ? pooled[(size_t)(n * 64 + c) * 300 + (tp - 1)] : 0.f;
  }
  __syncthreads();
  int t = threadIdx.x;
  if (t < 300) {
    float acc[16];
#pragma unroll
    for (int o = 0; o < 16; ++o) acc[o] = 0.f;
    for (int c = 0; c < 64; ++c) {
      const float* wr = lw1r + c * 48;  // uniform -> s_load into SGPRs
      float pk0 = p[c][t];
      float pk1 = p[c][t + 1];
      float pk2 = p[c][t + 2];
#pragma unroll
      for (int o = 0; o < 16; ++o) {
        acc[o] = fmaf(wr[o * 3 + 0], pk0, acc[o]);
        acc[o] = fmaf(wr[o * 3 + 1], pk1, acc[o]);
        acc[o] = fmaf(wr[o * 3 + 2], pk2, acc[o]);
      }
    }
#pragma unroll
    for (int o = 0; o < 16; ++o) {
      float v = acc[o] * BN_SCALE_F;
      z[o][t] = v > 0.f ? v : 0.f;
    }
  }
  __syncthreads();
  {
    int c = threadIdx.x / 5;
    int t4b = threadIdx.x - c * 5;
    const float* w2row = l_w2 + c * 16;
    float w2r[16];
#pragma unroll
    for (int o = 0; o < 16; ++o) w2r[o] = w2row[o];
    float* outp = la + ((size_t)(n * 64 + c)) * 300;
    for (int it = 0; it < 15; ++it) {
      int t4 = t4b + it * 5;
      float4 s = {0.f, 0.f, 0.f, 0.f};
#pragma unroll
      for (int o = 0; o < 16; ++o) {
        float4 zv = *(const float4*)(&z[o][t4 * 4]);
        float wo = w2r[o];
        s.x = fmaf(zv.x, wo, s.x);
        s.y = fmaf(zv.y, wo, s.y);
        s.z = fmaf(zv.z, wo, s.z);
        s.w = fmaf(zv.w, wo, s.w);
      }
      float4 r;
      r.x = 1.f / (1.f + expf(-s.x));
      r.y = 1.f / (1.f + expf(-s.y));
      r.z = 1.f / (1.f + expf(-s.z));
      r.w = 1.f / (1.f + expf(-s.w));
      *(float4*)(&outp[t4 * 4]) = r;
    }
  }
}

// ---------------- Kernel 4: final conv — LDS la + depth-2 x prefetch ----------------
__global__ __launch_bounds__(256) void tam_final_kernel(const float* __restrict__ x,
                                                        const float* __restrict__ la,
                                                        const float* __restrict__ kern,
                                                        float* __restrict__ out) {
  __shared__ float la_s[64][40];  // t0-1 .. t0+38
  int bid = blockIdx.x;  // 64 n * 8 tchunk * 2 half
  int n = bid >> 4;
  int rem = bid & 15;
  int tch = rem >> 1;
  int half = rem & 1;
  int t0 = tch * 38;
  // cooperative la stage (all threads)
  for (int i = threadIdx.x; i < 2560; i += 256) {
    int c = i / 40, tt = i - c * 40;
    int gt = t0 - 1 + tt;
    la_s[c][tt] = (gt >= 0 && gt < 300) ? la[(size_t)(n * 64 + c) * 300 + gt] : 0.f;
  }
  __syncthreads();

  int cv4 = half * 256 + threadIdx.x;
  if (cv4 >= 400) return;
  int e0 = cv4 * 4;
  int c0 = e0 / 25;
  int c3 = (e0 + 3) / 25;
  bool s1 = ((e0 + 1) / 25) != c0;
  bool s2 = ((e0 + 2) / 25) != c0;
  bool s3 = (c3 != c0);
  const float* kp0 = kern + (size_t)(n * 64 + c0) * 3;
  const float* kp1 = kern + (size_t)(n * 64 + c3) * 3;
  float k00 = kp0[0], k01 = kp0[1], k02 = kp0[2];
  float k10 = kp1[0], k11 = kp1[1], k12 = kp1[2];
  float4 K0 = {k00, s1 ? k10 : k00, s2 ? k10 : k00, s3 ? k10 : k00};
  float4 K1 = {k01, s1 ? k11 : k01, s2 ? k11 : k01, s3 ? k11 : k01};
  float4 K2 = {k02, s1 ? k12 : k02, s2 ? k12 : k02, s3 ? k12 : k02};

  const float4* xp = (const float4*)(x + (size_t)n * 480000) + cv4;  // +t*400
  float4* op = (float4*)(out + (size_t)n * 480000) + cv4;

  int tend = t0 + 38;
  if (tend > 300) tend = 300;

#define YMAKE(dst, XV, IDX)                  \
  {                                          \
    float l0 = la_s[c0][(IDX)];              \
    float l1 = la_s[c3][(IDX)];              \
    dst.x = XV.x * l0;                       \
    dst.y = XV.y * (s1 ? l1 : l0);           \
    dst.z = XV.z * (s2 ? l1 : l0);           \
    dst.w = XV.w * (s3 ? l1 : l0);           \
  }

  float4 am, ac;
  if (t0 > 0) {
    float4 xv = xp[(size_t)(t0 - 1) * 400];
    YMAKE(am, xv, 0);
  } else {
    am = {0.f, 0.f, 0.f, 0.f};
  }
  {
    float4 xv = xp[(size_t)t0 * 400];
    YMAKE(ac, xv, 1);
  }
  // pipeline: xn1 = x(t+1), xn2 = x(t+2) at loop top
  float4 xn1 = xp[(size_t)(t0 + 1) * 400];
  float4 xn2 = xp[(size_t)(t0 + 2 < 300 ? t0 + 2 : 299) * 400];

  for (int t = t0; t < tend; ++t) {
    int t3 = t + 3;
    if (t3 > 299) t3 = 299;
    float4 xn3 = xp[(size_t)t3 * 400];  // issue early; used in 2 iters
    float4 an;
    if (t + 1 < 300) {
      YMAKE(an, xn1, t - t0 + 2);
    } else {
      an = {0.f, 0.f, 0.f, 0.f};
    }
    float4 o;
    o.x = fmaf(am.x, K0.x, fmaf(ac.x, K1.x, an.x * K2.x));
    o.y = fmaf(am.y, K0.y, fmaf(ac.y, K1.y, an.y * K2.y));
    o.z = fmaf(am.z, K0.z, fmaf(ac.z, K1.z, an.z * K2.z));
    o.w = fmaf(am.w, K0.w, fmaf(ac.w, K1.w, an.w * K2.w));
    op[(size_t)t * 400] = o;
    am = ac;
    ac = an;
    xn1 = xn2;
    xn2 = xn3;
  }
#undef YMAKE
}

extern "C" void kernel_launch(void* const* d_in, const int* in_sizes, int n_in,
                              void* d_out, int out_size, void* d_ws, size_t ws_size,
                              hipStream_t stream) {
  const float* x = (const float*)d_in[0];
  const float* g_w1 = (const float*)d_in[1];
  const float* g_w2 = (const float*)d_in[2];
  const float* l_w1 = (const float*)d_in[3];
  const float* l_w2 = (const float*)d_in[4];
  float* out = (float*)d_out;
  float* ws = (float*)d_ws;
  float* pooled = ws;                           // 1,228,800 floats
  float* kern = ws + 1228800;                   // 12,288
  float* lact = ws + 1228800 + 12288;           // 1,228,800
  float* w1p = ws + 1228800 + 12288 + 1228800;  // 180,000
  float* lw1r = w1p + 180000;                   // 3,072

  hipLaunchKernelGGL(pool_prep_kernel, dim3(4851), dim3(256), 0, stream, x, g_w1, l_w1,
                     pooled, w1p, lw1r);
  hipLaunchKernelGGL(g_kernel, dim3(256), dim3(640), 0, stream, pooled, w1p, g_w2, kern);
  hipLaunchKernelGGL(l_kernel, dim3(64), dim3(320), 0, stream, pooled, lw1r, l_w2, lact);
  hipLaunchKernelGGL(tam_final_kernel, dim3(1024), dim3(256), 0, stream, x, lact, kern, out);
}